// Round 1
// baseline (367.501 us; speedup 1.0000x reference)
//
#include <hip/hip_runtime.h>

#define K1 16
#define NC 32
#define NP 4096
#define NB 16
#define NE (NP * K1)

__device__ __forceinline__ float relu_f(float x) { return x > 0.f ? x : 0.f; }

// One block: 16 points of one batch. Thread = (p_local = tid>>4, k = tid&15).
// Weights are read via wave-uniform global addresses -> scalar loads (s_load),
// broadcast for free; no LDS traffic for weights.
__global__ __launch_bounds__(256) void fused_edgeconv(
    const float* __restrict__ feat,   // (B, C, P)
    const int*   __restrict__ edge,   // (B, 2, E)
    const float* __restrict__ w0,     // (32, 64)
    const float* __restrict__ g0, const float* __restrict__ b0,
    const float* __restrict__ w1,     // (32, 32)
    const float* __restrict__ g1, const float* __restrict__ b1,
    const float* __restrict__ w2,     // (64, 32)
    const float* __restrict__ g2, const float* __restrict__ b2,
    const float* __restrict__ scw,    // (64, 32)
    const float* __restrict__ scg, const float* __restrict__ scb,
    float* __restrict__ out)          // (B, 64, P)
{
    const float INVC = 0.9999950000374997f;  // 1/sqrt(1+1e-5)

    __shared__ float sF[16][33];    // center features, +1 pad
    __shared__ float sFts[16][65];  // summed h2 per point

    const int tid = threadIdx.x;
    const int blk = blockIdx.x;      // 4096 blocks = 16 b * 256 tiles
    const int b   = blk >> 8;
    const int p0  = (blk & 255) << 4;

    const float* fb = feat + (size_t)b * NC * NP;

    // stage the 16 center points' 32 channels
    for (int i = tid; i < 16 * 32; i += 256) {
        int c = i >> 4, pl = i & 15;
        sF[pl][c] = fb[c * NP + p0 + pl];
    }
    __syncthreads();

    const int pl = tid >> 4;
    const int k  = tid & 15;
    const int p  = p0 + pl;
    // idx[b,p,k] = edge_features[b,1,p*K1+k]  (run structure of setup data)
    const int q  = edge[(size_t)b * 2 * NE + NE + p * K1 + k];

    // load gathered features (strided, L2-resident) and center; d = fq - fp
    float fp[NC], d[NC];
    #pragma unroll
    for (int c = 0; c < NC; ++c) fp[c] = sF[pl][c];
    #pragma unroll
    for (int c = 0; c < NC; ++c) d[c] = fb[c * NP + q] - fp[c];

    // layer 0: (32 x 64) over concat(fp, d)
    float h0[32];
    #pragma unroll
    for (int o = 0; o < 32; ++o) {
        float acc = 0.f;
        #pragma unroll
        for (int c = 0; c < 32; ++c) acc = fmaf(w0[o * 64 + c], fp[c], acc);
        #pragma unroll
        for (int c = 0; c < 32; ++c) acc = fmaf(w0[o * 64 + 32 + c], d[c], acc);
        h0[o] = relu_f(fmaf(acc, g0[o] * INVC, b0[o]));
    }

    // layer 1: (32 x 32)
    float h1[32];
    #pragma unroll
    for (int o = 0; o < 32; ++o) {
        float acc = 0.f;
        #pragma unroll
        for (int c = 0; c < 32; ++c) acc = fmaf(w1[o * 32 + c], h0[c], acc);
        h1[o] = relu_f(fmaf(acc, g1[o] * INVC, b1[o]));
    }

    // layer 2: (64 x 32), fused with k-reduction (sum over the 16 k-lanes)
    #pragma unroll
    for (int o = 0; o < 64; ++o) {
        float acc = 0.f;
        #pragma unroll
        for (int c = 0; c < 32; ++c) acc = fmaf(w2[o * 32 + c], h1[c], acc);
        float v = relu_f(fmaf(acc, g2[o] * INVC, b2[o]));
        v += __shfl_xor(v, 1, 16);
        v += __shfl_xor(v, 2, 16);
        v += __shfl_xor(v, 4, 16);
        v += __shfl_xor(v, 8, 16);
        if ((o & 15) == k) sFts[pl][o] = v;
    }
    __syncthreads();

    // epilogue: shortcut matvec + mean + relu; 1024 (o,pj) pairs / 256 threads
    #pragma unroll
    for (int i = 0; i < 4; ++i) {
        int pair = tid + (i << 8);
        int o  = pair >> 4;
        int pj = pair & 15;
        float acc = 0.f;
        #pragma unroll
        for (int c = 0; c < 32; ++c) acc = fmaf(scw[o * 32 + c], sF[pj][c], acc);
        acc = fmaf(acc, scg[o] * INVC, scb[o]) + sFts[pj][o] * (1.0f / 16.0f);
        out[(size_t)b * 64 * NP + o * NP + p0 + pj] = relu_f(acc);
    }
}

extern "C" void kernel_launch(void* const* d_in, const int* in_sizes, int n_in,
                              void* d_out, int out_size, void* d_ws, size_t ws_size,
                              hipStream_t stream) {
    // inputs: 0 points (unused), 1 features, 2 edge_features,
    // 3 conv_w0, 4 bn_g0, 5 bn_b0, 6 conv_w1, 7 bn_g1, 8 bn_b1,
    // 9 conv_w2, 10 bn_g2, 11 bn_b2, 12 sc_w, 13 sc_g, 14 sc_b
    const float* feat = (const float*)d_in[1];
    const int*   edge = (const int*)d_in[2];
    const float* w0   = (const float*)d_in[3];
    const float* g0   = (const float*)d_in[4];
    const float* b0   = (const float*)d_in[5];
    const float* w1   = (const float*)d_in[6];
    const float* g1   = (const float*)d_in[7];
    const float* b1   = (const float*)d_in[8];
    const float* w2   = (const float*)d_in[9];
    const float* g2   = (const float*)d_in[10];
    const float* b2   = (const float*)d_in[11];
    const float* scw  = (const float*)d_in[12];
    const float* scg  = (const float*)d_in[13];
    const float* scb  = (const float*)d_in[14];
    float* outp = (float*)d_out;

    const int blocks = NB * (NP / 16);  // 4096
    fused_edgeconv<<<blocks, 256, 0, stream>>>(
        feat, edge, w0, g0, b0, w1, g1, b1, w2, g2, b2, scw, scg, scb, outp);
}

// Round 2
// 177.589 us; speedup vs baseline: 2.0694x; 2.0694x over previous
//
#include <hip/hip_runtime.h>
#include <hip/hip_bf16.h>

#define K1 16
#define NC 32
#define NP 4096
#define NB 16
#define NE (NP * K1)

typedef __attribute__((ext_vector_type(8))) short bf16x8;
typedef __attribute__((ext_vector_type(4))) float f32x4;

__device__ __forceinline__ float bf2f(short u) {
    union { unsigned int i; float f; } x;
    x.i = ((unsigned int)(unsigned short)u) << 16;
    return x.f;
}
__device__ __forceinline__ short f2bf(float f) {
    return (short)__bfloat16_as_ushort(__float2bfloat16(f));
}
__device__ __forceinline__ float relu_f(float x) { return x > 0.f ? x : 0.f; }

// ---- prep 1: transpose features (B,C,P) fp32 -> (B,P,C) bf16 ----
__global__ __launch_bounds__(256) void transpose_feat(
    const float* __restrict__ feat, short* __restrict__ featT)
{
    int i = blockIdx.x * 256 + threadIdx.x;   // over B*P = 65536
    int b = i >> 12;
    int p = i & (NP - 1);
    const float* src = feat + (size_t)b * NC * NP + p;
    short row[NC];
    #pragma unroll
    for (int c = 0; c < NC; ++c) row[c] = f2bf(src[c * NP]);
    short* dst = featT + (size_t)i * NC;
    #pragma unroll
    for (int j = 0; j < 4; ++j)
        ((bf16x8*)dst)[j] = ((const bf16x8*)row)[j];
}

// ---- prep 2: fold BN scale into weights, convert to bf16 ----
__global__ __launch_bounds__(256) void fold_weights(
    const float* __restrict__ w0, const float* __restrict__ g0,
    const float* __restrict__ w1, const float* __restrict__ g1,
    const float* __restrict__ w2, const float* __restrict__ g2,
    const float* __restrict__ scw, const float* __restrict__ scg,
    short* __restrict__ w0f, short* __restrict__ w1f, short* __restrict__ w2f,
    float* __restrict__ scwf)
{
    const float INVC = 0.9999950000374997f;   // 1/sqrt(1+1e-5)
    int i = blockIdx.x * 256 + threadIdx.x;
    if (i < 2048) {
        w0f[i] = f2bf(w0[i] * g0[i >> 6] * INVC);          // (32,64)
    } else if (i < 3072) {
        int j = i - 2048; w1f[j] = f2bf(w1[j] * g1[j >> 5] * INVC);  // (32,32)
    } else if (i < 5120) {
        int j = i - 3072; w2f[j] = f2bf(w2[j] * g2[j >> 5] * INVC);  // (64,32)
    } else if (i < 7168) {
        int j = i - 5120; scwf[j] = scw[j] * scg[j >> 5] * INVC;     // (64,32) fp32
    }
}

// XOR-swizzled LDS helpers for [256][32] bf16 tiles (64B rows, 4x16B chunks)
__device__ __forceinline__ void st_h(short* H, int row, int col, short v) {
    int sw = (col >> 3) ^ (row & 3);
    H[row * 32 + sw * 8 + (col & 7)] = v;
}
__device__ __forceinline__ bf16x8 ld_h(const short* H, int row, int g) {
    int sw = g ^ (row & 3);
    return *(const bf16x8*)(H + row * 32 + sw * 16 / 2);
}

// ---- main: fused 3-layer edgeconv via MFMA ----
__global__ __launch_bounds__(256) void edgeconv_mfma(
    const float* __restrict__ feat, const int* __restrict__ edge,
    const short* __restrict__ featT,
    const short* __restrict__ w0f, const float* __restrict__ b0,
    const short* __restrict__ w1f, const float* __restrict__ b1,
    const short* __restrict__ w2f, const float* __restrict__ b2,
    const float* __restrict__ scwf, const float* __restrict__ scb,
    float* __restrict__ out)
{
    __shared__ short H0[256 * 32];
    __shared__ short H1[256 * 32];
    __shared__ float sF[16][33];
    __shared__ float sFts[16][65];

    const int tid  = threadIdx.x;
    const int wv   = tid >> 6;
    const int lane = tid & 63;
    const int lr   = lane & 15;   // row-in-tile (A) / col (B,D)
    const int g    = lane >> 4;   // k-group
    const int b    = blockIdx.x >> 8;
    const int p0   = (blockIdx.x & 255) << 4;
    const int rbase = wv * 64;

    // stage center features fp32 for the shortcut epilogue
    for (int i = tid; i < 16 * 32; i += 256) {
        int c = i >> 4, pl = i & 15;
        sF[pl][c] = feat[((size_t)b * NC + c) * NP + p0 + pl];
    }

    // ---------------- layer 0: X(256x64) * W0'^T(64x32) ----------------
    bf16x8 wB0[2][2];
    #pragma unroll
    for (int nt = 0; nt < 2; ++nt)
        #pragma unroll
        for (int ks = 0; ks < 2; ++ks)
            wB0[nt][ks] = *(const bf16x8*)(w0f + (nt * 16 + lr) * 64 + ks * 32 + g * 8);

    f32x4 acc0[4][2] = {};
    #pragma unroll
    for (int rt = 0; rt < 4; ++rt) {
        const int pt = wv * 4 + rt;            // point 0..15 in tile
        const int p  = p0 + pt;
        const int q  = edge[(size_t)b * 2 * NE + NE + p * K1 + lr];
        const short* fpRow = featT + ((size_t)(b * NP) + p) * NC;
        const short* fqRow = featT + ((size_t)(b * NP) + q) * NC;
        bf16x8 aF0 = *(const bf16x8*)(fpRow + g * 8);   // fp chunk (k=0..31)
        bf16x8 fq8 = *(const bf16x8*)(fqRow + g * 8);
        bf16x8 aF1;                                     // d = fq - fp (k=32..63)
        #pragma unroll
        for (int j = 0; j < 8; ++j)
            aF1[j] = f2bf(bf2f(fq8[j]) - bf2f(aF0[j]));
        #pragma unroll
        for (int nt = 0; nt < 2; ++nt) {
            acc0[rt][nt] = __builtin_amdgcn_mfma_f32_16x16x32_bf16(aF0, wB0[nt][0], acc0[rt][nt], 0, 0, 0);
            acc0[rt][nt] = __builtin_amdgcn_mfma_f32_16x16x32_bf16(aF1, wB0[nt][1], acc0[rt][nt], 0, 0, 0);
        }
    }
    // bias + relu -> H0 (bf16, swizzled)
    #pragma unroll
    for (int rt = 0; rt < 4; ++rt)
        #pragma unroll
        for (int nt = 0; nt < 2; ++nt) {
            int col = nt * 16 + lr;
            float bias = b0[col];
            #pragma unroll
            for (int i = 0; i < 4; ++i) {
                int row = rbase + rt * 16 + g * 4 + i;
                st_h(H0, row, col, f2bf(relu_f(acc0[rt][nt][i] + bias)));
            }
        }
    __syncthreads();

    // ---------------- layer 1: H0(256x32) * W1'^T(32x32) ----------------
    bf16x8 wB1[2];
    #pragma unroll
    for (int nt = 0; nt < 2; ++nt)
        wB1[nt] = *(const bf16x8*)(w1f + (nt * 16 + lr) * 32 + g * 8);

    f32x4 acc1[4][2] = {};
    #pragma unroll
    for (int rt = 0; rt < 4; ++rt) {
        bf16x8 a = ld_h(H0, rbase + rt * 16 + lr, g);
        #pragma unroll
        for (int nt = 0; nt < 2; ++nt)
            acc1[rt][nt] = __builtin_amdgcn_mfma_f32_16x16x32_bf16(a, wB1[nt], acc1[rt][nt], 0, 0, 0);
    }
    #pragma unroll
    for (int rt = 0; rt < 4; ++rt)
        #pragma unroll
        for (int nt = 0; nt < 2; ++nt) {
            int col = nt * 16 + lr;
            float bias = b1[col];
            #pragma unroll
            for (int i = 0; i < 4; ++i) {
                int row = rbase + rt * 16 + g * 4 + i;
                st_h(H1, row, col, f2bf(relu_f(acc1[rt][nt][i] + bias)));
            }
        }
    __syncthreads();

    // ---------------- layer 2: H1(256x32) * W2'^T(32x64) + k-mean -------
    bf16x8 wB2[4];
    #pragma unroll
    for (int nt = 0; nt < 4; ++nt)
        wB2[nt] = *(const bf16x8*)(w2f + (nt * 16 + lr) * 32 + g * 8);

    f32x4 acc2[4][4] = {};
    #pragma unroll
    for (int rt = 0; rt < 4; ++rt) {
        bf16x8 a = ld_h(H1, rbase + rt * 16 + lr, g);
        #pragma unroll
        for (int nt = 0; nt < 4; ++nt)
            acc2[rt][nt] = __builtin_amdgcn_mfma_f32_16x16x32_bf16(a, wB2[nt], acc2[rt][nt], 0, 0, 0);
    }
    // bias + relu + sum over the 16 edges of each point (rows of each tile)
    #pragma unroll
    for (int rt = 0; rt < 4; ++rt) {
        const int pt = wv * 4 + rt;
        #pragma unroll
        for (int nt = 0; nt < 4; ++nt) {
            int col = nt * 16 + lr;
            float bias = b2[col];
            float s = 0.f;
            #pragma unroll
            for (int i = 0; i < 4; ++i)
                s += relu_f(acc2[rt][nt][i] + bias);
            s += __shfl_xor(s, 16, 64);
            s += __shfl_xor(s, 32, 64);
            if (lane < 16) sFts[pt][col] = s;
        }
    }
    __syncthreads();

    // ---------------- epilogue: fp32 shortcut + mean + relu -------------
    #pragma unroll
    for (int it = 0; it < 4; ++it) {
        int pair = tid + (it << 8);
        int o  = pair >> 4;
        int pj = pair & 15;
        float acc = 0.f;
        #pragma unroll
        for (int c = 0; c < NC; ++c)
            acc = fmaf(scwf[o * 32 + c], sF[pj][c], acc);
        float val = acc + scb[o] + sFts[pj][o] * (1.0f / 16.0f);
        out[((size_t)b * 64 + o) * NP + p0 + pj] = relu_f(val);
    }
}

extern "C" void kernel_launch(void* const* d_in, const int* in_sizes, int n_in,
                              void* d_out, int out_size, void* d_ws, size_t ws_size,
                              hipStream_t stream) {
    const float* feat = (const float*)d_in[1];
    const int*   edge = (const int*)d_in[2];
    const float* w0   = (const float*)d_in[3];
    const float* g0   = (const float*)d_in[4];
    const float* b0   = (const float*)d_in[5];
    const float* w1   = (const float*)d_in[6];
    const float* g1   = (const float*)d_in[7];
    const float* b1   = (const float*)d_in[8];
    const float* w2   = (const float*)d_in[9];
    const float* g2   = (const float*)d_in[10];
    const float* b2   = (const float*)d_in[11];
    const float* scw  = (const float*)d_in[12];
    const float* scg  = (const float*)d_in[13];
    const float* scb  = (const float*)d_in[14];
    float* outp = (float*)d_out;

    char* ws = (char*)d_ws;
    short* featT = (short*)ws;                       // 16*4096*32*2 = 4,194,304 B
    short* w0f   = (short*)(ws + 4194304);           // 4096 B
    short* w1f   = (short*)(ws + 4198400);           // 2048 B
    short* w2f   = (short*)(ws + 4200448);           // 4096 B
    float* scwf  = (float*)(ws + 4204544);           // 8192 B

    transpose_feat<<<256, 256, 0, stream>>>(feat, featT);
    fold_weights<<<28, 256, 0, stream>>>(w0, g0, w1, g1, w2, g2, scw, scg,
                                         w0f, w1f, w2f, scwf);
    edgeconv_mfma<<<NB * (NP / 16), 256, 0, stream>>>(
        feat, edge, featT, w0f, b0, w1f, b1, w2f, b2, scwf, scb, outp);
}

// Round 3
// 132.526 us; speedup vs baseline: 2.7730x; 1.3400x over previous
//
#include <hip/hip_runtime.h>
#include <hip/hip_bf16.h>

#define K1 16
#define NC 32
#define NP 4096
#define NB 16
#define NE (NP * K1)

typedef __attribute__((ext_vector_type(8))) short bf16x8;
typedef __attribute__((ext_vector_type(4))) float f32x4;

__device__ __forceinline__ float bf2f(short u) {
    union { unsigned int i; float f; } x;
    x.i = ((unsigned int)(unsigned short)u) << 16;
    return x.f;
}
__device__ __forceinline__ short f2bf(float f) {
    return (short)__bfloat16_as_ushort(__float2bfloat16(f));
}
__device__ __forceinline__ float relu_f(float x) { return x > 0.f ? x : 0.f; }

// k-slot permutation: hardware slot (g,e) holds logical channel kappa(g,e).
// Chosen so a D-fragment (lane owns rows {g*4+i} of two 16-row o-tiles) is
// directly the next layer's A/B fragment with NO cross-lane movement.
__device__ __forceinline__ int kappa(int g, int e) {
    return (e < 4) ? (g * 4 + e) : (16 + g * 4 + (e - 4));
}

// ---- prep: feature transpose to kappa-order bf16 + BN-folded kappa-order weights ----
__global__ __launch_bounds__(256) void prep(
    const float* __restrict__ feat,
    const float* __restrict__ w0, const float* __restrict__ g0,
    const float* __restrict__ w1, const float* __restrict__ g1,
    const float* __restrict__ w2, const float* __restrict__ g2,
    const float* __restrict__ scw, const float* __restrict__ scg,
    short* __restrict__ featTp, short* __restrict__ w0p,
    short* __restrict__ w1p, short* __restrict__ w2p, short* __restrict__ scwp)
{
    const float INVC = 0.9999950000374997f;   // 1/sqrt(1+1e-5)
    const int blk = blockIdx.x;
    if (blk < 256) {
        int i = blk * 256 + threadIdx.x;      // point id over B*P = 65536
        int b = i >> 12, p = i & (NP - 1);
        const float* src = feat + (size_t)b * NC * NP + p;
        float row[NC];
        #pragma unroll
        for (int c = 0; c < NC; ++c) row[c] = src[c * NP];
        short o16[32];
        #pragma unroll
        for (int g = 0; g < 4; ++g)
            #pragma unroll
            for (int e = 0; e < 8; ++e)
                o16[g * 8 + e] = f2bf(row[kappa(g, e)]);
        short* dst = featTp + (size_t)i * 32;
        #pragma unroll
        for (int j = 0; j < 4; ++j)
            ((bf16x8*)dst)[j] = ((const bf16x8*)o16)[j];
    } else {
        const int t = threadIdx.x;
        for (int idx = t; idx < 2048; idx += 256) {        // w0p: (32 o) x (2 kc) x 32
            int o = idx >> 6, rem = idx & 63, kc = rem >> 5, pos = rem & 31;
            int g = pos >> 3, e = pos & 7;
            w0p[idx] = f2bf(w0[o * 64 + kc * 32 + kappa(g, e)] * g0[o] * INVC);
        }
        for (int idx = t; idx < 1024; idx += 256) {        // w1p: 32 x 32
            int o = idx >> 5, pos = idx & 31, g = pos >> 3, e = pos & 7;
            w1p[idx] = f2bf(w1[o * 32 + kappa(g, e)] * g1[o] * INVC);
        }
        for (int idx = t; idx < 2048; idx += 256) {        // w2p: 64 x 32
            int o = idx >> 5, pos = idx & 31, g = pos >> 3, e = pos & 7;
            w2p[idx] = f2bf(w2[o * 32 + kappa(g, e)] * g2[o] * INVC);
        }
        for (int idx = t; idx < 2048; idx += 256) {        // scwp: 64 x 32
            int o = idx >> 5, pos = idx & 31, g = pos >> 3, e = pos & 7;
            scwp[idx] = f2bf(scw[o * 32 + kappa(g, e)] * scg[o] * INVC);
        }
    }
}

// ---- main: register-resident 3-layer chain + shortcut, no barriers ----
__global__ __launch_bounds__(256, 4) void edgeconv_mfma(
    const int* __restrict__ edge, const short* __restrict__ featTp,
    const float* __restrict__ b0, const float* __restrict__ b1,
    const float* __restrict__ b2,
    const short* __restrict__ w0p, const short* __restrict__ w1p,
    const short* __restrict__ w2p, const short* __restrict__ scwp,
    const float* __restrict__ scb, float* __restrict__ out)
{
    __shared__ float sFts[4][16][68];   // [wave][pt][o], padded: conflict-free

    const int tid  = threadIdx.x;
    const int wv   = tid >> 6;
    const int lane = tid & 63;
    const int lr   = lane & 15;
    const int g    = lane >> 4;

    // XCD-contiguous swizzle: 1024 blocks, 8 XCDs, 128 blocks each
    const int bid = blockIdx.x;
    const int swz = (bid & 7) * 128 + (bid >> 3);
    const int b   = swz >> 6;                       // batch
    const int p0w = ((swz & 63) << 6) + wv * 16;    // wave's first point

    // persistent fragments (kappa-ordered weights)
    bf16x8 wA0[2][2], wA1[2], wB2[4];
    #pragma unroll
    for (int nt = 0; nt < 2; ++nt)
        #pragma unroll
        for (int kc = 0; kc < 2; ++kc)
            wA0[nt][kc] = *(const bf16x8*)(w0p + (nt * 16 + lr) * 64 + kc * 32 + g * 8);
    #pragma unroll
    for (int nt = 0; nt < 2; ++nt)
        wA1[nt] = *(const bf16x8*)(w1p + (nt * 16 + lr) * 32 + g * 8);
    #pragma unroll
    for (int nt = 0; nt < 4; ++nt)
        wB2[nt] = *(const bf16x8*)(w2p + (nt * 16 + lr) * 32 + g * 8);

    f32x4 bias0[2] = { *(const f32x4*)(b0 + g * 4), *(const f32x4*)(b0 + 16 + g * 4) };
    f32x4 bias1[2] = { *(const f32x4*)(b1 + g * 4), *(const f32x4*)(b1 + 16 + g * 4) };
    float bc2[4];
    #pragma unroll
    for (int nt = 0; nt < 4; ++nt) bc2[nt] = b2[nt * 16 + lr];

    const int*   eb = edge + (size_t)b * 2 * NE + NE;
    const short* fT = featTp + (size_t)b * NP * 32;

    #pragma unroll 4
    for (int rt = 0; rt < 16; ++rt) {
        const int p = p0w + rt;
        const int q = eb[p * K1 + lr];
        bf16x8 xf0 = *(const bf16x8*)(fT + p * 32 + g * 8);   // fp (uniform over r)
        bf16x8 fq  = *(const bf16x8*)(fT + (size_t)q * 32 + g * 8);
        bf16x8 xd;
        #pragma unroll
        for (int e = 0; e < 8; ++e) xd[e] = f2bf(bf2f(fq[e]) - bf2f(xf0[e]));

        // L0 (swapped): D0[o][r] = W0' * [fp; d]^T
        f32x4 acc0[2] = {{0.f,0.f,0.f,0.f},{0.f,0.f,0.f,0.f}};
        #pragma unroll
        for (int nt = 0; nt < 2; ++nt) {
            acc0[nt] = __builtin_amdgcn_mfma_f32_16x16x32_bf16(wA0[nt][0], xf0, acc0[nt], 0, 0, 0);
            acc0[nt] = __builtin_amdgcn_mfma_f32_16x16x32_bf16(wA0[nt][1], xd,  acc0[nt], 0, 0, 0);
        }
        // D-frag IS the next B-frag in kappa-order: bias+relu+cvt only
        bf16x8 h0;
        #pragma unroll
        for (int e = 0; e < 4; ++e) {
            h0[e]     = f2bf(relu_f(acc0[0][e] + bias0[0][e]));
            h0[e + 4] = f2bf(relu_f(acc0[1][e] + bias0[1][e]));
        }
        // L1 (swapped): D1[o][r]
        f32x4 acc1[2] = {{0.f,0.f,0.f,0.f},{0.f,0.f,0.f,0.f}};
        #pragma unroll
        for (int nt = 0; nt < 2; ++nt)
            acc1[nt] = __builtin_amdgcn_mfma_f32_16x16x32_bf16(wA1[nt], h0, acc1[nt], 0, 0, 0);
        bf16x8 h1;
        #pragma unroll
        for (int e = 0; e < 4; ++e) {
            h1[e]     = f2bf(relu_f(acc1[0][e] + bias1[0][e]));
            h1[e + 4] = f2bf(relu_f(acc1[1][e] + bias1[1][e]));
        }
        // L2 (standard): D2[r][o] — h1-frag doubles as the A operand
        f32x4 acc2[4] = {{0.f,0.f,0.f,0.f},{0.f,0.f,0.f,0.f},{0.f,0.f,0.f,0.f},{0.f,0.f,0.f,0.f}};
        #pragma unroll
        for (int nt = 0; nt < 4; ++nt)
            acc2[nt] = __builtin_amdgcn_mfma_f32_16x16x32_bf16(h1, wB2[nt], acc2[nt], 0, 0, 0);

        // relu + mean over the 16 edges (rows): local 4 + xor16 + xor32
        float f0, f1, f2, f3;
        #pragma unroll
        for (int nt = 0; nt < 4; ++nt) {
            float s = relu_f(acc2[nt][0] + bc2[nt]) + relu_f(acc2[nt][1] + bc2[nt])
                    + relu_f(acc2[nt][2] + bc2[nt]) + relu_f(acc2[nt][3] + bc2[nt]);
            s += __shfl_xor(s, 16, 64);
            s += __shfl_xor(s, 32, 64);
            if (nt == 0) f0 = s; else if (nt == 1) f1 = s; else if (nt == 2) f2 = s; else f3 = s;
        }
        float sel = (g == 0) ? f0 : (g == 1) ? f1 : (g == 2) ? f2 : f3;
        sFts[wv][rt][g * 16 + lr] = sel;   // o = g*16+lr for this lane's g
    }

    // ---- shortcut: one option-1 MFMA set over the wave's 16 points ----
    bf16x8 aS = *(const bf16x8*)(fT + (p0w + lr) * 32 + g * 8);  // rows = points
    bf16x8 wS[4];
    #pragma unroll
    for (int nt = 0; nt < 4; ++nt)
        wS[nt] = *(const bf16x8*)(scwp + (nt * 16 + lr) * 32 + g * 8);
    float scbc[4];
    #pragma unroll
    for (int nt = 0; nt < 4; ++nt) scbc[nt] = scb[nt * 16 + lr];

    f32x4 accS[4] = {{0.f,0.f,0.f,0.f},{0.f,0.f,0.f,0.f},{0.f,0.f,0.f,0.f},{0.f,0.f,0.f,0.f}};
    #pragma unroll
    for (int nt = 0; nt < 4; ++nt)
        accS[nt] = __builtin_amdgcn_mfma_f32_16x16x32_bf16(aS, wS[nt], accS[nt], 0, 0, 0);

    float* ob = out + (size_t)b * 64 * NP;
    #pragma unroll
    for (int nt = 0; nt < 4; ++nt) {
        f32x4 v;
        #pragma unroll
        for (int i = 0; i < 4; ++i) {
            float fts = sFts[wv][g * 4 + i][nt * 16 + lr];
            v[i] = relu_f(accS[nt][i] + scbc[nt] + fts * 0.0625f);
        }
        *(f32x4*)(ob + (nt * 16 + lr) * NP + p0w + g * 4) = v;
    }
}

extern "C" void kernel_launch(void* const* d_in, const int* in_sizes, int n_in,
                              void* d_out, int out_size, void* d_ws, size_t ws_size,
                              hipStream_t stream) {
    const float* feat = (const float*)d_in[1];
    const int*   edge = (const int*)d_in[2];
    const float* w0   = (const float*)d_in[3];
    const float* g0   = (const float*)d_in[4];
    const float* b0   = (const float*)d_in[5];
    const float* w1   = (const float*)d_in[6];
    const float* g1   = (const float*)d_in[7];
    const float* b1   = (const float*)d_in[8];
    const float* w2   = (const float*)d_in[9];
    const float* g2   = (const float*)d_in[10];
    const float* b2   = (const float*)d_in[11];
    const float* scw  = (const float*)d_in[12];
    const float* scg  = (const float*)d_in[13];
    const float* scb  = (const float*)d_in[14];
    float* outp = (float*)d_out;

    char* ws = (char*)d_ws;
    short* featTp = (short*)ws;                 // 16*4096*32*2 = 4,194,304 B
    short* w0p    = (short*)(ws + 4194304);     // 4096 B
    short* w1p    = (short*)(ws + 4198400);     // 2048 B
    short* w2p    = (short*)(ws + 4200448);     // 4096 B
    short* scwp   = (short*)(ws + 4204544);     // 4096 B

    prep<<<257, 256, 0, stream>>>(feat, w0, g0, w1, g1, w2, g2, scw, scg,
                                  featTp, w0p, w1p, w2p, scwp);
    edgeconv_mfma<<<1024, 256, 0, stream>>>(
        edge, featTp, b0, b1, b2, w0p, w1p, w2p, scwp, scb, outp);
}